// Round 10
// baseline (178.951 us; speedup 1.0000x reference)
//
#include <hip/hip_runtime.h>

// B=4, C=512, L=2048, H=8, D=64. f32 inputs, f32 output.
// Universal fragment-packed layouts (r4). r5: attn 64 i-rows (67.2us). r8: 4-wave
// j-split, same 67.2 (VGPR 204 = 2 waves/SIMD). r9: sw-pipeline, VGPR 152, STILL
// ~68 -> diagnosis: LDS 53,248B x3 = 159,744 vs 160KB leaves no granularity
// margin -> still 2 blocks/CU; all TLP attempts were silently residency-capped.
// r10: *** CHUNKED COMBINE: the 52KB LDS existed only for the final 4-wave
// O-partial merge. Loop dt-chunks (4 x 13KB, 2 barriers each) -> LDS ~13.9KB.
// 3rd block/CU now unambiguous (VGPR 152 binds at exactly 3 waves/SIMD).
// Main loop byte-identical to r9. ***

#define LDIM 2048
#define CDIM 512
#define BATCH 4

typedef __attribute__((ext_vector_type(8))) short s16x8;
typedef __attribute__((ext_vector_type(4))) float f32x4;
typedef __attribute__((ext_vector_type(4))) unsigned short u16x4;
typedef unsigned int u32;
typedef unsigned short u16;

__device__ __forceinline__ u16 f2b(float f) {
    unsigned u = __float_as_uint(f);
    u += 0x7fffu + ((u >> 16) & 1u);   // RNE
    return (u16)(u >> 16);
}
// pack two floats -> two bf16 (round-half-up) in one u32 (b in high half)
__device__ __forceinline__ u32 pk2(float a, float b) {
    u32 ua = __float_as_uint(a) + 0x8000u;
    u32 ub = __float_as_uint(b) + 0x8000u;
    return __builtin_amdgcn_perm(ub, ua, 0x07060302u);  // {ub.hi16, ua.hi16}
}

// ---------------- unified transpose + f32->bf16 convert -> packed chunks -------
// chunk(row,col): elem(rtile*16+mn, cstep*32+q*8+e) at ((rtile*16+cstep)*64+lane)*8+e
__global__ __launch_bounds__(256)
void transpA_k(const float* __restrict__ x, const float* __restrict__ wq,
               const float* __restrict__ wo, u16* __restrict__ XP,
               u16* __restrict__ WP, u16* __restrict__ WOP)
{
    const int r0 = blockIdx.x * 64;
    const int y  = blockIdx.y;
    const float* in; u16* out; int inLD, c0;
    if (y < 128) {
        const int b = y >> 5, ct = y & 31;
        in = x + (size_t)b * CDIM * LDIM; inLD = LDIM; c0 = ct * 64;
        out = XP + (size_t)b * LDIM * CDIM;
    } else if (y < 152) {
        in = wq; inLD = 1536; c0 = (y - 128) * 64; out = WP;
    } else {
        in = wo; inLD = 512;  c0 = (y - 152) * 64; out = WOP;
    }

    __shared__ __align__(16) u16 t[64][80];
    const int tt = threadIdx.x;
    const int lr = tt >> 4, lc = (tt & 15) * 4;
    #pragma unroll
    for (int i = 0; i < 4; ++i) {
        f32x4 v = *(const f32x4*)(in + (size_t)(r0 + lr + i * 16) * inLD + c0 + lc);
        #pragma unroll
        for (int j = 0; j < 4; ++j) t[lc + j][lr + i * 16] = f2b(v[j]);
    }
    __syncthreads();
    const int orow = tt >> 2, ocg = (tt & 3) * 16;
    s16x8 v0 = *(const s16x8*)&t[orow][ocg];
    s16x8 v1 = *(const s16x8*)&t[orow][ocg + 8];
    const int row   = c0 + orow;            // l (or f) index
    const int rtile = row >> 4, rr = row & 15;
    const int cstep = (r0 + ocg) >> 5;      // 32-col step within CDIM-like axis
    const int qb    = (ocg >> 3) & 3;       // 0 or 2
    u16* dst = out + ((size_t)(rtile * 16 + cstep) * 64 + qb * 16 + rr) * 8;
    *(s16x8*)dst = v0;                      // q = qb   half
    *(s16x8*)(dst + 128) = v1;              // q = qb+1 half
}

// ---------------- QKV GEMM (r5 config): packed-chunk loads -> QF/KF/VF --------
__global__ __launch_bounds__(256)
void qkvgemm_bf16(const u16* __restrict__ XP, const u16* __restrict__ WP,
                  u16* __restrict__ QF, u16* __restrict__ KF, u16* __restrict__ VF)
{
    const int f0 = blockIdx.x * 64;
    const int l0 = blockIdx.y * 128;
    const int b  = blockIdx.z;
    const u16* xTb = XP + (size_t)b * LDIM * CDIM;
    const int t = threadIdx.x, w = t >> 6, lane = t & 63;
    const int mn = lane & 15, q = lane >> 4;
    const bool vpart = (f0 >= 1024);

    const u16 *Abase, *Bbase;
    int mbase, nbase;
    if (!vpart) {
        mbase = f0 + (w >> 1) * 32; nbase = l0 + (w & 1) * 64;
        Abase = WP + (size_t)mbase * CDIM; Bbase = xTb + (size_t)nbase * CDIM;
    } else {
        mbase = l0 + w * 32; nbase = f0;
        Abase = xTb + (size_t)mbase * CDIM; Bbase = WP + (size_t)nbase * CDIM;
    }

    f32x4 acc[2][4] = {};
    #pragma unroll 2
    for (int c0 = 0; c0 < CDIM; c0 += 32) {
        s16x8 a[2], bf[4];
        #pragma unroll
        for (int mi = 0; mi < 2; ++mi)
            a[mi] = *(const s16x8*)(Abase + mi * 16 * CDIM + c0 * 16 + lane * 8);
        #pragma unroll
        for (int ni = 0; ni < 4; ++ni)
            bf[ni] = *(const s16x8*)(Bbase + ni * 16 * CDIM + c0 * 16 + lane * 8);
        #pragma unroll
        for (int mi = 0; mi < 2; ++mi)
            #pragma unroll
            for (int ni = 0; ni < 4; ++ni)
                acc[mi][ni] = __builtin_amdgcn_mfma_f32_16x16x32_bf16(a[mi], bf[ni], acc[mi][ni], 0, 0, 0);
    }

    if (!vpart) {
        const int part = f0 >> 9;
        const float sc2 = (part == 0) ? 0.18033688f : 1.0f;  // 0.125*log2(e)
        u16* Tout = (part == 0) ? QF : KF;
        #pragma unroll
        for (int mi = 0; mi < 2; ++mi) {
            const int fg0 = mbase + mi * 16;
            const int h = (fg0 >> 6) & 7;
            const int d0 = (fg0 & 63) + q * 4;          // 4-aligned d base
            const int kd = d0 >> 5, qq = (d0 >> 3) & 3, e0 = d0 & 7;
            u16* T = Tout + (size_t)(b * 8 + h) * LDIM * 64;
            #pragma unroll
            for (int ni = 0; ni < 4; ++ni) {
                const int lg = nbase + ni * 16 + mn;     // L index
                size_t addr;
                if (part == 0) {                         // QF[t16][kd][lane][8]
                    const int t16 = lg >> 4, mnq = lg & 15;
                    addr = (size_t)((t16 * 2 + kd) * 512 + (qq * 16 + mnq) * 8 + e0);
                } else {                                 // KF[j64][jt][kd][lane][8], kperm absorbed
                    const int j64 = lg >> 6, r6 = lg & 63;
                    const int jt  = ((r6 >> 2) & 1) * 2 + (r6 >> 5);
                    const int mnk = ((r6 >> 3) & 3) * 4 + (r6 & 3);
                    addr = (size_t)(((j64 * 4 + jt) * 2 + kd) * 512 + (qq * 16 + mnk) * 8 + e0);
                }
                u16x4 pk;
                #pragma unroll
                for (int r = 0; r < 4; ++r) pk[r] = f2b(acc[mi][ni][r] * sc2);
                *(u16x4*)(T + addr) = pk;
            }
        }
    } else {
        #pragma unroll
        for (int ni = 0; ni < 4; ++ni) {
            const int fg = nbase + ni * 16 + mn;
            const int h = (fg >> 6) & 7;
            const int d = fg & 63;
            const int dt = d >> 4, mnv = d & 15;
            u16* Vb = VF + (size_t)(b * 8 + h) * LDIM * 64;
            #pragma unroll
            for (int mi = 0; mi < 2; ++mi) {
                const int lg0 = mbase + mi * 16 + q * 4;    // 4-aligned j base
                const int j64 = lg0 >> 6, j6 = lg0 & 63;
                const int kj = j6 >> 5, qq = (j6 >> 3) & 3, e0 = j6 & 7;
                const size_t addr = (size_t)(((j64 * 2 + kj) * 4 + dt) * 512 + (qq * 16 + mnv) * 8 + e0);
                u16x4 pk;
                #pragma unroll
                for (int r = 0; r < 4; ++r) pk[r] = f2b(acc[mi][ni][r]);
                *(u16x4*)(Vb + addr) = pk;
            }
        }
    }
}

// ---------------- Flash attention: 64 i-rows, 4-wave j-split, SW-pipelined ------
// grid (x=bh 32, y=32), 256 threads (4 waves). Wave wv owns j in [wv*512,(wv+1)*512).
// Main loop = r9. Combine = CHUNKED over dt (4 x ~13KB) -> LDS ~13.9KB total so
// 3 blocks/CU co-reside (VGPR 152 binds at 3 waves/SIMD).
__global__ __launch_bounds__(256)
void attn_k(const u16* __restrict__ QF, const u16* __restrict__ KF,
            const u16* __restrict__ VF, u16* __restrict__ aoP)
{
    const int bh = blockIdx.x;
    const int b = bh >> 3, h = bh & 7;
    const u16* Qh = QF + (size_t)bh * LDIM * 64;
    const u16* Kh = KF + (size_t)bh * LDIM * 64;
    const u16* Vh = VF + (size_t)bh * LDIM * 64;

    __shared__ __align__(16) float o_sh[3][64][17];   // ONE dt-chunk (+1 pad col)
    __shared__ float lp_sh[3][64];

    const int tid = threadIdx.x;
    const int wv = tid >> 6;
    const int lane = tid & 63;
    const int mn = lane & 15, q = lane >> 4;
    const int ib64 = blockIdx.y;         // 64-row i-block
    const int TH = 8;                    // j-tiles per wave (of 32 total)
    const int tbase = wv * TH;

    s16x8 aq[4][2];
    #pragma unroll
    for (int ibt = 0; ibt < 4; ++ibt) {
        const int t16 = ib64 * 4 + ibt;
        #pragma unroll
        for (int kd = 0; kd < 2; ++kd)
            aq[ibt][kd] = *(const s16x8*)(Qh + (size_t)((t16 * 2 + kd) * 512) + lane * 8);
    }

    f32x4 o_acc[4][4] = {};
    float lp[4] = {0.f, 0.f, 0.f, 0.f};

    s16x8 kc[2][4], vc[2][4], ap[2][4];

    // ---- prologue: tile 0 ----
    {
        const u16* Kt = Kh + (size_t)tbase * 4096;
        #pragma unroll
        for (int kd = 0; kd < 2; ++kd)
            #pragma unroll
            for (int jt = 0; jt < 4; ++jt)
                kc[kd][jt] = *(const s16x8*)(Kt + ((jt * 2 + kd) << 9) + (lane << 3));

        f32x4 s[4][4] = {};
        #pragma unroll
        for (int kd = 0; kd < 2; ++kd)
            #pragma unroll
            for (int jt = 0; jt < 4; ++jt)
                #pragma unroll
                for (int ibt = 0; ibt < 4; ++ibt)
                    s[ibt][jt] = __builtin_amdgcn_mfma_f32_16x16x32_bf16(kc[kd][jt], aq[ibt][kd], s[ibt][jt], 0, 0, 0);

        // reload kc = K(1) (after QK consumed it); load vc = V(0)
        const u16* Ktn = Kh + (size_t)(tbase + 1) * 4096;
        #pragma unroll
        for (int kd = 0; kd < 2; ++kd)
            #pragma unroll
            for (int jt = 0; jt < 4; ++jt)
                kc[kd][jt] = *(const s16x8*)(Ktn + ((jt * 2 + kd) << 9) + (lane << 3));
        const u16* Vt = Vh + (size_t)tbase * 4096;
        #pragma unroll
        for (int kj = 0; kj < 2; ++kj)
            #pragma unroll
            for (int dt = 0; dt < 4; ++dt)
                vc[kj][dt] = *(const s16x8*)(Vt + ((kj * 4 + dt) << 9) + (lane << 3));

        // exp/pack tile 0 -> ap
        #pragma unroll
        for (int kj = 0; kj < 2; ++kj)
            #pragma unroll
            for (int ibt = 0; ibt < 4; ++ibt) {
                float pa0 = __builtin_amdgcn_exp2f(s[ibt][kj][0]);
                float pa1 = __builtin_amdgcn_exp2f(s[ibt][kj][1]);
                float pa2 = __builtin_amdgcn_exp2f(s[ibt][kj][2]);
                float pa3 = __builtin_amdgcn_exp2f(s[ibt][kj][3]);
                float pb0 = __builtin_amdgcn_exp2f(s[ibt][kj + 2][0]);
                float pb1 = __builtin_amdgcn_exp2f(s[ibt][kj + 2][1]);
                float pb2 = __builtin_amdgcn_exp2f(s[ibt][kj + 2][2]);
                float pb3 = __builtin_amdgcn_exp2f(s[ibt][kj + 2][3]);
                lp[ibt] += ((pa0 + pa1) + (pa2 + pa3)) + ((pb0 + pb1) + (pb2 + pb3));
                union { s16x8 v; u32 w[4]; } u;
                u.w[0] = pk2(pa0, pa1);
                u.w[1] = pk2(pa2, pa3);
                u.w[2] = pk2(pb0, pb1);
                u.w[3] = pk2(pb2, pb3);
                ap[kj][ibt] = u.v;
            }
    }

    // ---- pipelined main loop: body jj does QK(jj+1), exp(jj+1) || PV(jj) ----
    for (int jj = 0; jj < TH - 1; ++jj) {
        // QK for tile jj+1 (kc holds K(jj+1))
        f32x4 s[4][4] = {};
        #pragma unroll
        for (int kd = 0; kd < 2; ++kd)
            #pragma unroll
            for (int jt = 0; jt < 4; ++jt)
                #pragma unroll
                for (int ibt = 0; ibt < 4; ++ibt)
                    s[ibt][jt] = __builtin_amdgcn_mfma_f32_16x16x32_bf16(kc[kd][jt], aq[ibt][kd], s[ibt][jt], 0, 0, 0);

        // reload kc = K(jj+2) (wrap; cover = exp/PV phase)
        {
            const u16* Ktn = Kh + (size_t)(tbase + ((jj + 2) & (TH - 1))) * 4096;
            #pragma unroll
            for (int kd = 0; kd < 2; ++kd)
                #pragma unroll
                for (int jt = 0; jt < 4; ++jt)
                    kc[kd][jt] = *(const s16x8*)(Ktn + ((jt * 2 + kd) << 9) + (lane << 3));
        }

        // exp/pack tile jj+1 (VALU) interleaved with PV tile jj (MFMA) — independent
        s16x8 apn[2][4];
        #pragma unroll
        for (int kj = 0; kj < 2; ++kj)
            #pragma unroll
            for (int ibt = 0; ibt < 4; ++ibt) {
                float pa0 = __builtin_amdgcn_exp2f(s[ibt][kj][0]);
                float pa1 = __builtin_amdgcn_exp2f(s[ibt][kj][1]);
                float pa2 = __builtin_amdgcn_exp2f(s[ibt][kj][2]);
                float pa3 = __builtin_amdgcn_exp2f(s[ibt][kj][3]);
                float pb0 = __builtin_amdgcn_exp2f(s[ibt][kj + 2][0]);
                float pb1 = __builtin_amdgcn_exp2f(s[ibt][kj + 2][1]);
                float pb2 = __builtin_amdgcn_exp2f(s[ibt][kj + 2][2]);
                float pb3 = __builtin_amdgcn_exp2f(s[ibt][kj + 2][3]);
                lp[ibt] += ((pa0 + pa1) + (pa2 + pa3)) + ((pb0 + pb1) + (pb2 + pb3));
                union { s16x8 v; u32 w[4]; } u;
                u.w[0] = pk2(pa0, pa1);
                u.w[1] = pk2(pa2, pa3);
                u.w[2] = pk2(pb0, pb1);
                u.w[3] = pk2(pb2, pb3);
                apn[kj][ibt] = u.v;
                // PV slice for tile jj (old ap) — hides the exp above
                #pragma unroll
                for (int dt = 0; dt < 4; ++dt)
                    o_acc[ibt][dt] = __builtin_amdgcn_mfma_f32_16x16x32_bf16(vc[kj][dt], ap[kj][ibt], o_acc[ibt][dt], 0, 0, 0);
            }

        // reload vc = V(jj+1) (after PV consumed it; cover = next QK+exp)
        {
            const u16* Vtn = Vh + (size_t)(tbase + jj + 1) * 4096;
            #pragma unroll
            for (int kj = 0; kj < 2; ++kj)
                #pragma unroll
                for (int dt = 0; dt < 4; ++dt)
                    vc[kj][dt] = *(const s16x8*)(Vtn + ((kj * 4 + dt) << 9) + (lane << 3));
        }

        // rotate packed P
        #pragma unroll
        for (int kj = 0; kj < 2; ++kj)
            #pragma unroll
            for (int ibt = 0; ibt < 4; ++ibt)
                ap[kj][ibt] = apn[kj][ibt];
    }

    // ---- epilogue: PV for last tile ----
    #pragma unroll
    for (int kj = 0; kj < 2; ++kj)
        #pragma unroll
        for (int ibt = 0; ibt < 4; ++ibt)
            #pragma unroll
            for (int dt = 0; dt < 4; ++dt)
                o_acc[ibt][dt] = __builtin_amdgcn_mfma_f32_16x16x32_bf16(vc[kj][dt], ap[kj][ibt], o_acc[ibt][dt], 0, 0, 0);

    #pragma unroll
    for (int ibt = 0; ibt < 4; ++ibt) {
        lp[ibt] += __shfl_xor(lp[ibt], 16);
        lp[ibt] += __shfl_xor(lp[ibt], 32);
    }

    // ---- chunked combine: lp first, then 4 dt-chunks through 13KB LDS ----
    if (wv != 0) {
        #pragma unroll
        for (int ibt = 0; ibt < 4; ++ibt)
            if (q == 0) lp_sh[wv - 1][ibt * 16 + mn] = lp[ibt];
    }
    __syncthreads();
    float rinv[4];
    if (wv == 0) {
        #pragma unroll
        for (int ibt = 0; ibt < 4; ++ibt) {
            const int row = ibt * 16 + mn;
            rinv[ibt] = 1.0f / (lp[ibt] + lp_sh[0][row] + lp_sh[1][row] + lp_sh[2][row]);
        }
    }
    u16* Ab = aoP + (size_t)b * LDIM * 512;
    #pragma unroll
    for (int dt = 0; dt < 4; ++dt) {
        __syncthreads();               // previous chunk fully consumed
        if (wv != 0) {
            #pragma unroll
            for (int ibt = 0; ibt < 4; ++ibt)
                *(f32x4*)&o_sh[wv - 1][ibt * 16 + mn][q * 4] = o_acc[ibt][dt];
        }
        __syncthreads();
        if (wv == 0) {
            #pragma unroll
            for (int ibt = 0; ibt < 4; ++ibt) {
                const int row = ibt * 16 + mn;
                f32x4 o0 = *(const f32x4*)&o_sh[0][row][q * 4];
                f32x4 o1 = *(const f32x4*)&o_sh[1][row][q * 4];
                f32x4 o2 = *(const f32x4*)&o_sh[2][row][q * 4];
                u16x4 pk;
                #pragma unroll
                for (int r = 0; r < 4; ++r)
                    pk[r] = f2b((o_acc[ibt][dt][r] + o0[r] + o1[r] + o2[r]) * rinv[ibt]);
                // packed-chunk store: col = h*64 + dt*16 + q*4 + r
                const int ltile = ib64 * 4 + ibt;
                const int cstep = h * 2 + (dt >> 1);
                const int lanep = ((dt & 1) * 2 + (q >> 1)) * 16 + mn;
                u16* dst = Ab + ((size_t)(ltile * 16 + cstep) * 64 + lanep) * 8 + (q & 1) * 4;
                *(u16x4*)dst = pk;
            }
        }
    }
}

// ---------------- Output GEMM (r5 config): packed-chunk loads ----------------
__global__ __launch_bounds__(256)
void outgemm_d(const u16* __restrict__ aoP, const u16* __restrict__ WOP,
               const float* __restrict__ bias, float* __restrict__ Y)
{
    const int f0 = blockIdx.x * 64;
    const int l0 = blockIdx.y * 128;
    const int b  = blockIdx.z;
    const int t = threadIdx.x, w = t >> 6, lane = t & 63;
    const int mn = lane & 15, q = lane >> 4;
    const int mbase = f0 + (w >> 1) * 32;
    const int nbase = l0 + (w & 1) * 64;
    const u16* Abase = WOP + (size_t)mbase * CDIM;
    const u16* Bbase = aoP + ((size_t)b * LDIM + nbase) * CDIM;
    float* Yb = Y + (size_t)b * CDIM * LDIM;

    f32x4 acc[2][4] = {};
    #pragma unroll 2
    for (int c0 = 0; c0 < CDIM; c0 += 32) {
        s16x8 a[2], bf[4];
        #pragma unroll
        for (int mi = 0; mi < 2; ++mi)
            a[mi] = *(const s16x8*)(Abase + mi * 16 * CDIM + c0 * 16 + lane * 8);
        #pragma unroll
        for (int ni = 0; ni < 4; ++ni)
            bf[ni] = *(const s16x8*)(Bbase + ni * 16 * CDIM + c0 * 16 + lane * 8);
        #pragma unroll
        for (int mi = 0; mi < 2; ++mi)
            #pragma unroll
            for (int ni = 0; ni < 4; ++ni)
                acc[mi][ni] = __builtin_amdgcn_mfma_f32_16x16x32_bf16(a[mi], bf[ni], acc[mi][ni], 0, 0, 0);
    }
    #pragma unroll
    for (int mi = 0; mi < 2; ++mi)
        #pragma unroll
        for (int r = 0; r < 4; ++r) {
            const int f = mbase + mi * 16 + q * 4 + r;
            const float bs = bias[f];
            #pragma unroll
            for (int ni = 0; ni < 4; ++ni)
                Yb[(size_t)f * LDIM + nbase + ni * 16 + mn] = acc[mi][ni][r] + bs;
        }
}

extern "C" void kernel_launch(void* const* d_in, const int* in_sizes, int n_in,
                              void* d_out, int out_size, void* d_ws, size_t ws_size,
                              hipStream_t stream) {
    const float *x = nullptr, *w_qkv = nullptr, *w_out = nullptr, *b_out = nullptr;
    for (int i = 0; i < n_in; ++i) {
        switch (in_sizes[i]) {
            case 4 * 512 * 2048: x     = (const float*)d_in[i]; break;
            case 512 * 1536:     w_qkv = (const float*)d_in[i]; break;
            case 512 * 512:      w_out = (const float*)d_in[i]; break;
            case 512:            b_out = (const float*)d_in[i]; break;
        }
    }
    float* out = (float*)d_out;                 // [4][512][2048] f32

    const size_t SLAB = (size_t)BATCH * LDIM * 512;      // 4194304 elems
    u16* WOP = (u16*)d_ws;                               // [512 rows][512] packed
    u16* XP  = WOP + (size_t)512 * 512;                  // [4][2048 rows][512] packed
    u16* WP  = XP + SLAB;                                // [1536 rows][512] packed
    u16* QF  = WP + (size_t)1536 * 512;                  // [32][2048*64] attn-packed
    u16* KF  = QF + SLAB;                                // [32][2048*64] attn-packed
    u16* VF  = KF + SLAB;                                // [32][2048*64] attn-packed
    u16* aoP = VF + SLAB;                                // [4][2048 rows][512] packed

    transpA_k<<<dim3(8, 160), 256, 0, stream>>>(x, w_qkv, w_out, XP, WP, WOP);
    qkvgemm_bf16<<<dim3(24, 16, BATCH), 256, 0, stream>>>(XP, WP, QF, KF, VF);
    attn_k<<<dim3(32, 32), 256, 0, stream>>>(QF, KF, VF, aoP);
    outgemm_d<<<dim3(8, 16, BATCH), 256, 0, stream>>>(aoP, WOP, b_out, out);
}

// Round 11
// 177.193 us; speedup vs baseline: 1.0099x; 1.0099x over previous
//
#include <hip/hip_runtime.h>

// B=4, C=512, L=2048, H=8, D=64. f32 inputs, f32 output.
// Universal fragment-packed layouts (r4): every MFMA operand LOAD is a
// lane-contiguous 1KB read. attn: r5 structure (best measured, 67.2us) —
// 64 i-rows/block, 2-wave j-split, K+V register prefetch. r8-r10 TLP attempts
// all flat -> attn is at its dataflow floor; reverted to r5 verbatim.
// r11: *** STORE-SIDE COALESCING (the never-touched half of r2's scatter
// diagnosis): qkvgemm's K/V/Q epilogue scattered 8B stores across 16 lines each
// (~3.1M line-requests). Every qkvgemm block's output is ONE contiguous 16KB
// span -> stage fragments in 16KB LDS (scatter there, <=2-way banks), barrier,
// copy out as 4x 1KB-per-wave linear stores. transpA stores remapped so each
// wave writes one contiguous 1KB chunk. Bytes bit-identical. ***

#define LDIM 2048
#define CDIM 512
#define BATCH 4

typedef __attribute__((ext_vector_type(8))) short s16x8;
typedef __attribute__((ext_vector_type(4))) float f32x4;
typedef __attribute__((ext_vector_type(4))) unsigned short u16x4;
typedef unsigned int u32;
typedef unsigned short u16;

__device__ __forceinline__ u16 f2b(float f) {
    unsigned u = __float_as_uint(f);
    u += 0x7fffu + ((u >> 16) & 1u);   // RNE
    return (u16)(u >> 16);
}
// pack two floats -> two bf16 (round-half-up) in one u32 (b in high half)
__device__ __forceinline__ u32 pk2(float a, float b) {
    u32 ua = __float_as_uint(a) + 0x8000u;
    u32 ub = __float_as_uint(b) + 0x8000u;
    return __builtin_amdgcn_perm(ub, ua, 0x07060302u);  // {ub.hi16, ua.hi16}
}

// ---------------- unified transpose + f32->bf16 convert -> packed chunks -------
// chunk(row,col): elem(rtile*16+mn, cstep*32+q*8+e) at ((rtile*16+cstep)*64+lane)*8+e
// r11: store phase remapped — wave w writes chunk (s*4+w): one contiguous 1KB.
__global__ __launch_bounds__(256)
void transpA_k(const float* __restrict__ x, const float* __restrict__ wq,
               const float* __restrict__ wo, u16* __restrict__ XP,
               u16* __restrict__ WP, u16* __restrict__ WOP)
{
    const int r0 = blockIdx.x * 64;
    const int y  = blockIdx.y;
    const float* in; u16* out; int inLD, c0;
    if (y < 128) {
        const int b = y >> 5, ct = y & 31;
        in = x + (size_t)b * CDIM * LDIM; inLD = LDIM; c0 = ct * 64;
        out = XP + (size_t)b * LDIM * CDIM;
    } else if (y < 152) {
        in = wq; inLD = 1536; c0 = (y - 128) * 64; out = WP;
    } else {
        in = wo; inLD = 512;  c0 = (y - 152) * 64; out = WOP;
    }

    __shared__ __align__(16) u16 t[64][80];
    const int tt = threadIdx.x;
    const int lr = tt >> 4, lc = (tt & 15) * 4;
    #pragma unroll
    for (int i = 0; i < 4; ++i) {
        f32x4 v = *(const f32x4*)(in + (size_t)(r0 + lr + i * 16) * inLD + c0 + lc);
        #pragma unroll
        for (int j = 0; j < 4; ++j) t[lc + j][lr + i * 16] = f2b(v[j]);
    }
    __syncthreads();
    // coalesced packed store: wave wvx writes chunk cidx = s*4+wvx contiguously
    const int lane = tt & 63;
    const int wvx = tt >> 6;
    const int qq = lane >> 4, mnq = lane & 15;
    #pragma unroll
    for (int s = 0; s < 2; ++s) {
        const int cidx = s * 4 + wvx;            // 0..7
        const int rt = cidx >> 1, cs = cidx & 1;
        s16x8 v = *(const s16x8*)&t[rt * 16 + mnq][cs * 32 + qq * 8];
        const int slot = ((c0 >> 4) + rt) * 16 + (r0 >> 5) + cs;
        *(s16x8*)(out + (size_t)slot * 512 + lane * 8) = v;
    }
}

// ---------------- QKV GEMM: packed loads; LDS-staged coalesced packed stores ---
// Each block's output = ONE contiguous 16KB span of QF/KF/VF.
__global__ __launch_bounds__(256)
void qkvgemm_bf16(const u16* __restrict__ XP, const u16* __restrict__ WP,
                  u16* __restrict__ QF, u16* __restrict__ KF, u16* __restrict__ VF)
{
    const int f0 = blockIdx.x * 64;
    const int l0 = blockIdx.y * 128;
    const int b  = blockIdx.z;
    const u16* xTb = XP + (size_t)b * LDIM * CDIM;
    const int t = threadIdx.x, w = t >> 6, lane = t & 63;
    const int mn = lane & 15, q = lane >> 4;
    const bool vpart = (f0 >= 1024);

    const u16 *Abase, *Bbase;
    int mbase, nbase;
    if (!vpart) {
        mbase = f0 + (w >> 1) * 32; nbase = l0 + (w & 1) * 64;
        Abase = WP + (size_t)mbase * CDIM; Bbase = xTb + (size_t)nbase * CDIM;
    } else {
        mbase = l0 + w * 32; nbase = f0;
        Abase = xTb + (size_t)mbase * CDIM; Bbase = WP + (size_t)nbase * CDIM;
    }

    f32x4 acc[2][4] = {};
    #pragma unroll 2
    for (int c0 = 0; c0 < CDIM; c0 += 32) {
        s16x8 a[2], bf[4];
        #pragma unroll
        for (int mi = 0; mi < 2; ++mi)
            a[mi] = *(const s16x8*)(Abase + mi * 16 * CDIM + c0 * 16 + lane * 8);
        #pragma unroll
        for (int ni = 0; ni < 4; ++ni)
            bf[ni] = *(const s16x8*)(Bbase + ni * 16 * CDIM + c0 * 16 + lane * 8);
        #pragma unroll
        for (int mi = 0; mi < 2; ++mi)
            #pragma unroll
            for (int ni = 0; ni < 4; ++ni)
                acc[mi][ni] = __builtin_amdgcn_mfma_f32_16x16x32_bf16(a[mi], bf[ni], acc[mi][ni], 0, 0, 0);
    }

    __shared__ __align__(16) u16 stg[8192];      // 16KB staging tile

    if (!vpart) {
        const int part = f0 >> 9;
        const float sc2 = (part == 0) ? 0.18033688f : 1.0f;  // 0.125*log2(e)
        #pragma unroll
        for (int mi = 0; mi < 2; ++mi) {
            const int fg0 = mbase + mi * 16;
            const int d0 = (fg0 & 63) + q * 4;          // 4-aligned d base
            const int kd = d0 >> 5, qq = (d0 >> 3) & 3, e0 = d0 & 7;
            #pragma unroll
            for (int ni = 0; ni < 4; ++ni) {
                const int lg = nbase + ni * 16 + mn;     // L index
                int addr;
                if (part == 0) {                         // QF[t16][kd][lane][8], local
                    const int t16l = (lg & 127) >> 4, mnq = lg & 15;
                    addr = (t16l * 2 + kd) * 512 + (qq * 16 + mnq) * 8 + e0;
                } else {                                 // KF[j64][jt][kd][lane][8], kperm absorbed
                    const int j64l = (lg & 127) >> 6, r6 = lg & 63;
                    const int jt  = ((r6 >> 2) & 1) * 2 + (r6 >> 5);
                    const int mnk = ((r6 >> 3) & 3) * 4 + (r6 & 3);
                    addr = ((j64l * 4 + jt) * 2 + kd) * 512 + (qq * 16 + mnk) * 8 + e0;
                }
                u16x4 pk;
                #pragma unroll
                for (int r = 0; r < 4; ++r) pk[r] = f2b(acc[mi][ni][r] * sc2);
                *(u16x4*)(stg + addr) = pk;
            }
        }
    } else {
        #pragma unroll
        for (int ni = 0; ni < 4; ++ni) {
            const int fg = nbase + ni * 16 + mn;
            const int d = fg & 63;
            const int dt = d >> 4, mnv = d & 15;
            #pragma unroll
            for (int mi = 0; mi < 2; ++mi) {
                const int lg0 = mbase + mi * 16 + q * 4;    // 4-aligned j base
                const int j64l = (lg0 & 127) >> 6, j6 = lg0 & 63;
                const int kj = j6 >> 5, qq = (j6 >> 3) & 3, e0 = j6 & 7;
                const int addr = ((j64l * 2 + kj) * 4 + dt) * 512 + (qq * 16 + mnv) * 8 + e0;
                u16x4 pk;
                #pragma unroll
                for (int r = 0; r < 4; ++r) pk[r] = f2b(acc[mi][ni][r]);
                *(u16x4*)(stg + addr) = pk;
            }
        }
    }

    __syncthreads();
    // linear copy: 4 x (256 threads x 16B) = 16KB, each wave 1KB contiguous
    const int h = (f0 >> 6) & 7;
    const size_t bhoff = (size_t)(b * 8 + h) * LDIM * 64;
    u16* T;
    if (!vpart) {
        const int part = f0 >> 9;
        T = ((part == 0) ? QF + bhoff + (size_t)(l0 >> 4) * 1024
                         : KF + bhoff + (size_t)(l0 >> 6) * 4096);
    } else {
        T = VF + bhoff + (size_t)(l0 >> 6) * 4096;
    }
    #pragma unroll
    for (int it = 0; it < 4; ++it)
        *(s16x8*)(T + it * 2048 + t * 8) = *(const s16x8*)(stg + it * 2048 + t * 8);
}

// ---------------- Flash attention (r5 verbatim): 64 i-rows, 2-wave j-split ------
// grid (x=bh 32, y=32), 128 threads (2 waves). All loads lane-contiguous 1KB.
__global__ __launch_bounds__(128)
void attn_k(const u16* __restrict__ QF, const u16* __restrict__ KF,
            const u16* __restrict__ VF, u16* __restrict__ aoP)
{
    const int bh = blockIdx.x;
    const int b = bh >> 3, h = bh & 7;
    const u16* Qh = QF + (size_t)bh * LDIM * 64;
    const u16* Kh = KF + (size_t)bh * LDIM * 64;
    const u16* Vh = VF + (size_t)bh * LDIM * 64;

    __shared__ __align__(16) float o_sh[64][68];   // +4 pad (2-way = free)
    __shared__ float lp_sh[64];

    const int tid = threadIdx.x;
    const int wv = tid >> 6;
    const int lane = tid & 63;
    const int mn = lane & 15, q = lane >> 4;
    const int ib64 = blockIdx.y;         // 64-row i-block
    const int TH = 16;                   // j-tiles per wave (of 32 total)
    const int tbase = wv * TH;

    s16x8 aq[4][2];
    #pragma unroll
    for (int ibt = 0; ibt < 4; ++ibt) {
        const int t16 = ib64 * 4 + ibt;
        #pragma unroll
        for (int kd = 0; kd < 2; ++kd)
            aq[ibt][kd] = *(const s16x8*)(Qh + (size_t)((t16 * 2 + kd) * 512) + lane * 8);
    }

    f32x4 o_acc[4][4] = {};
    float lp[4] = {0.f, 0.f, 0.f, 0.f};

    // preload this wave's tile-0 K/V fragments (fully coalesced)
    s16x8 kc[2][4], vc[2][4];
    {
        const u16* Kt = Kh + (size_t)tbase * 4096;
        const u16* Vt = Vh + (size_t)tbase * 4096;
        #pragma unroll
        for (int kd = 0; kd < 2; ++kd)
            #pragma unroll
            for (int jt = 0; jt < 4; ++jt)
                kc[kd][jt] = *(const s16x8*)(Kt + ((jt * 2 + kd) << 9) + (lane << 3));
        #pragma unroll
        for (int kj = 0; kj < 2; ++kj)
            #pragma unroll
            for (int dt = 0; dt < 4; ++dt)
                vc[kj][dt] = *(const s16x8*)(Vt + ((kj * 4 + dt) << 9) + (lane << 3));
    }

    #pragma unroll 2
    for (int jj = 0; jj < TH; ++jj) {
        const int tn = tbase + ((jj + 1) & (TH - 1));   // last iter wraps (L2-hot)
        const u16* Kt = Kh + (size_t)tn * 4096;
        const u16* Vt = Vh + (size_t)tn * 4096;

        // issue next tile's K loads FIRST
        s16x8 kn[2][4];
        #pragma unroll
        for (int kd = 0; kd < 2; ++kd)
            #pragma unroll
            for (int jt = 0; jt < 4; ++jt)
                kn[kd][jt] = *(const s16x8*)(Kt + ((jt * 2 + kd) << 9) + (lane << 3));

        // S^T = K.Q^T on current K: 32 MFMA (4 ibt)
        f32x4 s[4][4] = {};
        #pragma unroll
        for (int kd = 0; kd < 2; ++kd)
            #pragma unroll
            for (int jt = 0; jt < 4; ++jt)
                #pragma unroll
                for (int ibt = 0; ibt < 4; ++ibt)
                    s[ibt][jt] = __builtin_amdgcn_mfma_f32_16x16x32_bf16(kc[kd][jt], aq[ibt][kd], s[ibt][jt], 0, 0, 0);

        // issue next tile's V loads AFTER QK (staggered: caps VGPR peak)
        s16x8 vn[2][4];
        #pragma unroll
        for (int kj = 0; kj < 2; ++kj)
            #pragma unroll
            for (int dt = 0; dt < 4; ++dt)
                vn[kj][dt] = *(const s16x8*)(Vt + ((kj * 4 + dt) << 9) + (lane << 3));

        // p = 2^s; build PV B-fragments fully in-register (lane-local j-slots).
        #pragma unroll
        for (int kj = 0; kj < 2; ++kj) {
            s16x8 ap[4];
            #pragma unroll
            for (int ibt = 0; ibt < 4; ++ibt) {
                float pa0 = __builtin_amdgcn_exp2f(s[ibt][kj][0]);
                float pa1 = __builtin_amdgcn_exp2f(s[ibt][kj][1]);
                float pa2 = __builtin_amdgcn_exp2f(s[ibt][kj][2]);
                float pa3 = __builtin_amdgcn_exp2f(s[ibt][kj][3]);
                float pb0 = __builtin_amdgcn_exp2f(s[ibt][kj + 2][0]);
                float pb1 = __builtin_amdgcn_exp2f(s[ibt][kj + 2][1]);
                float pb2 = __builtin_amdgcn_exp2f(s[ibt][kj + 2][2]);
                float pb3 = __builtin_amdgcn_exp2f(s[ibt][kj + 2][3]);
                lp[ibt] += ((pa0 + pa1) + (pa2 + pa3)) + ((pb0 + pb1) + (pb2 + pb3));
                union { s16x8 v; u32 w[4]; } u;
                u.w[0] = pk2(pa0, pa1);
                u.w[1] = pk2(pa2, pa3);
                u.w[2] = pk2(pb0, pb1);
                u.w[3] = pk2(pb2, pb3);
                ap[ibt] = u.v;
            }
            #pragma unroll
            for (int dt = 0; dt < 4; ++dt)
                #pragma unroll
                for (int ibt = 0; ibt < 4; ++ibt)
                    o_acc[ibt][dt] = __builtin_amdgcn_mfma_f32_16x16x32_bf16(vc[kj][dt], ap[ibt], o_acc[ibt][dt], 0, 0, 0);
        }

        // rotate prefetched registers
        #pragma unroll
        for (int kd = 0; kd < 2; ++kd)
            #pragma unroll
            for (int jt = 0; jt < 4; ++jt)
                kc[kd][jt] = kn[kd][jt];
        #pragma unroll
        for (int kj = 0; kj < 2; ++kj)
            #pragma unroll
            for (int dt = 0; dt < 4; ++dt)
                vc[kj][dt] = vn[kj][dt];
    }

    #pragma unroll
    for (int ibt = 0; ibt < 4; ++ibt) {
        lp[ibt] += __shfl_xor(lp[ibt], 16);
        lp[ibt] += __shfl_xor(lp[ibt], 32);
    }

    // combine the two waves' j-partials: plain addition (sum-normalized softmax)
    if (wv == 1) {
        #pragma unroll
        for (int ibt = 0; ibt < 4; ++ibt) {
            #pragma unroll
            for (int dt = 0; dt < 4; ++dt)
                *(f32x4*)&o_sh[ibt * 16 + mn][dt * 16 + q * 4] = o_acc[ibt][dt];
            if (q == 0) lp_sh[ibt * 16 + mn] = lp[ibt];
        }
    }
    __syncthreads();
    if (wv == 0) {
        u16* Ab = aoP + (size_t)b * LDIM * 512;
        #pragma unroll
        for (int ibt = 0; ibt < 4; ++ibt) {
            const float rinv = 1.0f / (lp[ibt] + lp_sh[ibt * 16 + mn]);
            const int ltile = ib64 * 4 + ibt;
            #pragma unroll
            for (int dt = 0; dt < 4; ++dt) {
                f32x4 os = *(const f32x4*)&o_sh[ibt * 16 + mn][dt * 16 + q * 4];
                u16x4 pk;
                #pragma unroll
                for (int r = 0; r < 4; ++r)
                    pk[r] = f2b((o_acc[ibt][dt][r] + os[r]) * rinv);
                // packed-chunk store: col = h*64 + dt*16 + q*4 + r
                const int cstep = h * 2 + (dt >> 1);
                const int lanep = ((dt & 1) * 2 + (q >> 1)) * 16 + mn;
                u16* dst = Ab + ((size_t)(ltile * 16 + cstep) * 64 + lanep) * 8 + (q & 1) * 4;
                *(u16x4*)dst = pk;
            }
        }
    }
}

// ---------------- Output GEMM (r5 config): packed-chunk loads ----------------
__global__ __launch_bounds__(256)
void outgemm_d(const u16* __restrict__ aoP, const u16* __restrict__ WOP,
               const float* __restrict__ bias, float* __restrict__ Y)
{
    const int f0 = blockIdx.x * 64;
    const int l0 = blockIdx.y * 128;
    const int b  = blockIdx.z;
    const int t = threadIdx.x, w = t >> 6, lane = t & 63;
    const int mn = lane & 15, q = lane >> 4;
    const int mbase = f0 + (w >> 1) * 32;
    const int nbase = l0 + (w & 1) * 64;
    const u16* Abase = WOP + (size_t)mbase * CDIM;
    const u16* Bbase = aoP + ((size_t)b * LDIM + nbase) * CDIM;
    float* Yb = Y + (size_t)b * CDIM * LDIM;

    f32x4 acc[2][4] = {};
    #pragma unroll 2
    for (int c0 = 0; c0 < CDIM; c0 += 32) {
        s16x8 a[2], bf[4];
        #pragma unroll
        for (int mi = 0; mi < 2; ++mi)
            a[mi] = *(const s16x8*)(Abase + mi * 16 * CDIM + c0 * 16 + lane * 8);
        #pragma unroll
        for (int ni = 0; ni < 4; ++ni)
            bf[ni] = *(const s16x8*)(Bbase + ni * 16 * CDIM + c0 * 16 + lane * 8);
        #pragma unroll
        for (int mi = 0; mi < 2; ++mi)
            #pragma unroll
            for (int ni = 0; ni < 4; ++ni)
                acc[mi][ni] = __builtin_amdgcn_mfma_f32_16x16x32_bf16(a[mi], bf[ni], acc[mi][ni], 0, 0, 0);
    }
    #pragma unroll
    for (int mi = 0; mi < 2; ++mi)
        #pragma unroll
        for (int r = 0; r < 4; ++r) {
            const int f = mbase + mi * 16 + q * 4 + r;
            const float bs = bias[f];
            #pragma unroll
            for (int ni = 0; ni < 4; ++ni)
                Yb[(size_t)f * LDIM + nbase + ni * 16 + mn] = acc[mi][ni][r] + bs;
        }
}

extern "C" void kernel_launch(void* const* d_in, const int* in_sizes, int n_in,
                              void* d_out, int out_size, void* d_ws, size_t ws_size,
                              hipStream_t stream) {
    const float *x = nullptr, *w_qkv = nullptr, *w_out = nullptr, *b_out = nullptr;
    for (int i = 0; i < n_in; ++i) {
        switch (in_sizes[i]) {
            case 4 * 512 * 2048: x     = (const float*)d_in[i]; break;
            case 512 * 1536:     w_qkv = (const float*)d_in[i]; break;
            case 512 * 512:      w_out = (const float*)d_in[i]; break;
            case 512:            b_out = (const float*)d_in[i]; break;
        }
    }
    float* out = (float*)d_out;                 // [4][512][2048] f32

    const size_t SLAB = (size_t)BATCH * LDIM * 512;      // 4194304 elems
    u16* WOP = (u16*)d_ws;                               // [512 rows][512] packed
    u16* XP  = WOP + (size_t)512 * 512;                  // [4][2048 rows][512] packed
    u16* WP  = XP + SLAB;                                // [1536 rows][512] packed
    u16* QF  = WP + (size_t)1536 * 512;                  // [32][2048*64] attn-packed
    u16* KF  = QF + SLAB;                                // [32][2048*64] attn-packed
    u16* VF  = KF + SLAB;                                // [32][2048*64] attn-packed
    u16* aoP = VF + SLAB;                                // [4][2048 rows][512] packed

    transpA_k<<<dim3(8, 160), 256, 0, stream>>>(x, w_qkv, w_out, XP, WP, WOP);
    qkvgemm_bf16<<<dim3(24, 16, BATCH), 256, 0, stream>>>(XP, WP, QF, KF, VF);
    attn_k<<<dim3(32, 32), 128, 0, stream>>>(QF, KF, VF, aoP);
    outgemm_d<<<dim3(8, 16, BATCH), 256, 0, stream>>>(aoP, WOP, b_out, out);
}

// Round 12
// 169.529 us; speedup vs baseline: 1.0556x; 1.0452x over previous
//
#include <hip/hip_runtime.h>

// B=4, C=512, L=2048, H=8, D=64. f32 inputs, f32 output.
// Universal fragment-packed layouts (r4): every MFMA operand LOAD is a
// lane-contiguous 1KB read; r11 store-side coalescing (LDS-staged qkv stores,
// chunked transpA stores). attn: r5 structure (best measured, 65.7us here).
// r12: *** XCD-REUSE SWIZZLE for the GEMMs: pool (~110us) was invariant to
// load-count (r6) and store-pattern (r11) changes -> theory: B-tile reuse
// (24 sharer-blocks per 131KB xT tile in qkvgemm, 16 in outgemm) is scattered
// across all 8 XCD L2s by the default round-robin wgid%8 mapping -> ~400MB of
// L3 traffic. Flatten grids, wg = xf*64 + (b*16+y) so wg%8 = y%8: all sharers
// of one B-tile land on ONE XCD; resident B-set/XCD ~1MB << 4MB L2. attn is
// already naturally pinned (wg%8 = bh%8) - untouched. ***

#define LDIM 2048
#define CDIM 512
#define BATCH 4

typedef __attribute__((ext_vector_type(8))) short s16x8;
typedef __attribute__((ext_vector_type(4))) float f32x4;
typedef __attribute__((ext_vector_type(4))) unsigned short u16x4;
typedef unsigned int u32;
typedef unsigned short u16;

__device__ __forceinline__ u16 f2b(float f) {
    unsigned u = __float_as_uint(f);
    u += 0x7fffu + ((u >> 16) & 1u);   // RNE
    return (u16)(u >> 16);
}
// pack two floats -> two bf16 (round-half-up) in one u32 (b in high half)
__device__ __forceinline__ u32 pk2(float a, float b) {
    u32 ua = __float_as_uint(a) + 0x8000u;
    u32 ub = __float_as_uint(b) + 0x8000u;
    return __builtin_amdgcn_perm(ub, ua, 0x07060302u);  // {ub.hi16, ua.hi16}
}

// ---------------- unified transpose + f32->bf16 convert -> packed chunks -------
// chunk(row,col): elem(rtile*16+mn, cstep*32+q*8+e) at ((rtile*16+cstep)*64+lane)*8+e
// store phase: wave w writes chunk (s*4+w): one contiguous 1KB (r11).
__global__ __launch_bounds__(256)
void transpA_k(const float* __restrict__ x, const float* __restrict__ wq,
               const float* __restrict__ wo, u16* __restrict__ XP,
               u16* __restrict__ WP, u16* __restrict__ WOP)
{
    const int r0 = blockIdx.x * 64;
    const int y  = blockIdx.y;
    const float* in; u16* out; int inLD, c0;
    if (y < 128) {
        const int b = y >> 5, ct = y & 31;
        in = x + (size_t)b * CDIM * LDIM; inLD = LDIM; c0 = ct * 64;
        out = XP + (size_t)b * LDIM * CDIM;
    } else if (y < 152) {
        in = wq; inLD = 1536; c0 = (y - 128) * 64; out = WP;
    } else {
        in = wo; inLD = 512;  c0 = (y - 152) * 64; out = WOP;
    }

    __shared__ __align__(16) u16 t[64][80];
    const int tt = threadIdx.x;
    const int lr = tt >> 4, lc = (tt & 15) * 4;
    #pragma unroll
    for (int i = 0; i < 4; ++i) {
        f32x4 v = *(const f32x4*)(in + (size_t)(r0 + lr + i * 16) * inLD + c0 + lc);
        #pragma unroll
        for (int j = 0; j < 4; ++j) t[lc + j][lr + i * 16] = f2b(v[j]);
    }
    __syncthreads();
    // coalesced packed store: wave wvx writes chunk cidx = s*4+wvx contiguously
    const int lane = tt & 63;
    const int wvx = tt >> 6;
    const int qq = lane >> 4, mnq = lane & 15;
    #pragma unroll
    for (int s = 0; s < 2; ++s) {
        const int cidx = s * 4 + wvx;            // 0..7
        const int rt = cidx >> 1, cs = cidx & 1;
        s16x8 v = *(const s16x8*)&t[rt * 16 + mnq][cs * 32 + qq * 8];
        const int slot = ((c0 >> 4) + rt) * 16 + (r0 >> 5) + cs;
        *(s16x8*)(out + (size_t)slot * 512 + lane * 8) = v;
    }
}

// ---------------- QKV GEMM: packed loads; LDS-staged stores; XCD swizzle -------
// 1-D grid 1536: wg = xf*64 + (b*16+y)  ->  wg%8 = y%8: all 24 blocks sharing
// one xT B-tile (same l0,b) land on the same XCD L2.
__global__ __launch_bounds__(256)
void qkvgemm_bf16(const u16* __restrict__ XP, const u16* __restrict__ WP,
                  u16* __restrict__ QF, u16* __restrict__ KF, u16* __restrict__ VF)
{
    const int wg = blockIdx.x;
    const int xf = wg >> 6;              // 0..23
    const int yz = wg & 63;              // b*16 + y
    const int b  = yz >> 4;
    const int l0 = (yz & 15) * 128;
    const int f0 = xf * 64;
    const u16* xTb = XP + (size_t)b * LDIM * CDIM;
    const int t = threadIdx.x, w = t >> 6, lane = t & 63;
    const int mn = lane & 15, q = lane >> 4;
    const bool vpart = (f0 >= 1024);

    const u16 *Abase, *Bbase;
    int mbase, nbase;
    if (!vpart) {
        mbase = f0 + (w >> 1) * 32; nbase = l0 + (w & 1) * 64;
        Abase = WP + (size_t)mbase * CDIM; Bbase = xTb + (size_t)nbase * CDIM;
    } else {
        mbase = l0 + w * 32; nbase = f0;
        Abase = xTb + (size_t)mbase * CDIM; Bbase = WP + (size_t)nbase * CDIM;
    }

    f32x4 acc[2][4] = {};
    #pragma unroll 2
    for (int c0 = 0; c0 < CDIM; c0 += 32) {
        s16x8 a[2], bf[4];
        #pragma unroll
        for (int mi = 0; mi < 2; ++mi)
            a[mi] = *(const s16x8*)(Abase + mi * 16 * CDIM + c0 * 16 + lane * 8);
        #pragma unroll
        for (int ni = 0; ni < 4; ++ni)
            bf[ni] = *(const s16x8*)(Bbase + ni * 16 * CDIM + c0 * 16 + lane * 8);
        #pragma unroll
        for (int mi = 0; mi < 2; ++mi)
            #pragma unroll
            for (int ni = 0; ni < 4; ++ni)
                acc[mi][ni] = __builtin_amdgcn_mfma_f32_16x16x32_bf16(a[mi], bf[ni], acc[mi][ni], 0, 0, 0);
    }

    __shared__ __align__(16) u16 stg[8192];      // 16KB staging tile

    if (!vpart) {
        const int part = f0 >> 9;
        const float sc2 = (part == 0) ? 0.18033688f : 1.0f;  // 0.125*log2(e)
        #pragma unroll
        for (int mi = 0; mi < 2; ++mi) {
            const int fg0 = mbase + mi * 16;
            const int d0 = (fg0 & 63) + q * 4;          // 4-aligned d base
            const int kd = d0 >> 5, qq = (d0 >> 3) & 3, e0 = d0 & 7;
            #pragma unroll
            for (int ni = 0; ni < 4; ++ni) {
                const int lg = nbase + ni * 16 + mn;     // L index
                int addr;
                if (part == 0) {                         // QF[t16][kd][lane][8], local
                    const int t16l = (lg & 127) >> 4, mnq = lg & 15;
                    addr = (t16l * 2 + kd) * 512 + (qq * 16 + mnq) * 8 + e0;
                } else {                                 // KF[j64][jt][kd][lane][8], kperm absorbed
                    const int j64l = (lg & 127) >> 6, r6 = lg & 63;
                    const int jt  = ((r6 >> 2) & 1) * 2 + (r6 >> 5);
                    const int mnk = ((r6 >> 3) & 3) * 4 + (r6 & 3);
                    addr = ((j64l * 4 + jt) * 2 + kd) * 512 + (qq * 16 + mnk) * 8 + e0;
                }
                u16x4 pk;
                #pragma unroll
                for (int r = 0; r < 4; ++r) pk[r] = f2b(acc[mi][ni][r] * sc2);
                *(u16x4*)(stg + addr) = pk;
            }
        }
    } else {
        #pragma unroll
        for (int ni = 0; ni < 4; ++ni) {
            const int fg = nbase + ni * 16 + mn;
            const int d = fg & 63;
            const int dt = d >> 4, mnv = d & 15;
            #pragma unroll
            for (int mi = 0; mi < 2; ++mi) {
                const int lg0 = mbase + mi * 16 + q * 4;    // 4-aligned j base
                const int j64l = (lg0 & 127) >> 6, j6 = lg0 & 63;
                const int kj = j6 >> 5, qq = (j6 >> 3) & 3, e0 = j6 & 7;
                const int addr = ((j64l * 2 + kj) * 4 + dt) * 512 + (qq * 16 + mnv) * 8 + e0;
                u16x4 pk;
                #pragma unroll
                for (int r = 0; r < 4; ++r) pk[r] = f2b(acc[mi][ni][r]);
                *(u16x4*)(stg + addr) = pk;
            }
        }
    }

    __syncthreads();
    // linear copy: 4 x (256 threads x 16B) = 16KB, each wave 1KB contiguous
    const int h = (f0 >> 6) & 7;
    const size_t bhoff = (size_t)(b * 8 + h) * LDIM * 64;
    u16* T;
    if (!vpart) {
        const int part = f0 >> 9;
        T = ((part == 0) ? QF + bhoff + (size_t)(l0 >> 4) * 1024
                         : KF + bhoff + (size_t)(l0 >> 6) * 4096);
    } else {
        T = VF + bhoff + (size_t)(l0 >> 6) * 4096;
    }
    #pragma unroll
    for (int it = 0; it < 4; ++it)
        *(s16x8*)(T + it * 2048 + t * 8) = *(const s16x8*)(stg + it * 2048 + t * 8);
}

// ---------------- Flash attention (r5 verbatim): 64 i-rows, 2-wave j-split ------
// grid (x=bh 32, y=32), 128 threads (2 waves). wg%8 = bh%8: naturally XCD-pinned.
__global__ __launch_bounds__(128)
void attn_k(const u16* __restrict__ QF, const u16* __restrict__ KF,
            const u16* __restrict__ VF, u16* __restrict__ aoP)
{
    const int bh = blockIdx.x;
    const int b = bh >> 3, h = bh & 7;
    const u16* Qh = QF + (size_t)bh * LDIM * 64;
    const u16* Kh = KF + (size_t)bh * LDIM * 64;
    const u16* Vh = VF + (size_t)bh * LDIM * 64;

    __shared__ __align__(16) float o_sh[64][68];   // +4 pad (2-way = free)
    __shared__ float lp_sh[64];

    const int tid = threadIdx.x;
    const int wv = tid >> 6;
    const int lane = tid & 63;
    const int mn = lane & 15, q = lane >> 4;
    const int ib64 = blockIdx.y;         // 64-row i-block
    const int TH = 16;                   // j-tiles per wave (of 32 total)
    const int tbase = wv * TH;

    s16x8 aq[4][2];
    #pragma unroll
    for (int ibt = 0; ibt < 4; ++ibt) {
        const int t16 = ib64 * 4 + ibt;
        #pragma unroll
        for (int kd = 0; kd < 2; ++kd)
            aq[ibt][kd] = *(const s16x8*)(Qh + (size_t)((t16 * 2 + kd) * 512) + lane * 8);
    }

    f32x4 o_acc[4][4] = {};
    float lp[4] = {0.f, 0.f, 0.f, 0.f};

    // preload this wave's tile-0 K/V fragments (fully coalesced)
    s16x8 kc[2][4], vc[2][4];
    {
        const u16* Kt = Kh + (size_t)tbase * 4096;
        const u16* Vt = Vh + (size_t)tbase * 4096;
        #pragma unroll
        for (int kd = 0; kd < 2; ++kd)
            #pragma unroll
            for (int jt = 0; jt < 4; ++jt)
                kc[kd][jt] = *(const s16x8*)(Kt + ((jt * 2 + kd) << 9) + (lane << 3));
        #pragma unroll
        for (int kj = 0; kj < 2; ++kj)
            #pragma unroll
            for (int dt = 0; dt < 4; ++dt)
                vc[kj][dt] = *(const s16x8*)(Vt + ((kj * 4 + dt) << 9) + (lane << 3));
    }

    #pragma unroll 2
    for (int jj = 0; jj < TH; ++jj) {
        const int tn = tbase + ((jj + 1) & (TH - 1));   // last iter wraps (L2-hot)
        const u16* Kt = Kh + (size_t)tn * 4096;
        const u16* Vt = Vh + (size_t)tn * 4096;

        // issue next tile's K loads FIRST
        s16x8 kn[2][4];
        #pragma unroll
        for (int kd = 0; kd < 2; ++kd)
            #pragma unroll
            for (int jt = 0; jt < 4; ++jt)
                kn[kd][jt] = *(const s16x8*)(Kt + ((jt * 2 + kd) << 9) + (lane << 3));

        // S^T = K.Q^T on current K: 32 MFMA (4 ibt)
        f32x4 s[4][4] = {};
        #pragma unroll
        for (int kd = 0; kd < 2; ++kd)
            #pragma unroll
            for (int jt = 0; jt < 4; ++jt)
                #pragma unroll
                for (int ibt = 0; ibt < 4; ++ibt)
                    s[ibt][jt] = __builtin_amdgcn_mfma_f32_16x16x32_bf16(kc[kd][jt], aq[ibt][kd], s[ibt][jt], 0, 0, 0);

        // issue next tile's V loads AFTER QK (staggered: caps VGPR peak)
        s16x8 vn[2][4];
        #pragma unroll
        for (int kj = 0; kj < 2; ++kj)
            #pragma unroll
            for (int dt = 0; dt < 4; ++dt)
                vn[kj][dt] = *(const s16x8*)(Vt + ((kj * 4 + dt) << 9) + (lane << 3));

        // p = 2^s; build PV B-fragments fully in-register (lane-local j-slots).
        #pragma unroll
        for (int kj = 0; kj < 2; ++kj) {
            s16x8 ap[4];
            #pragma unroll
            for (int ibt = 0; ibt < 4; ++ibt) {
                float pa0 = __builtin_amdgcn_exp2f(s[ibt][kj][0]);
                float pa1 = __builtin_amdgcn_exp2f(s[ibt][kj][1]);
                float pa2 = __builtin_amdgcn_exp2f(s[ibt][kj][2]);
                float pa3 = __builtin_amdgcn_exp2f(s[ibt][kj][3]);
                float pb0 = __builtin_amdgcn_exp2f(s[ibt][kj + 2][0]);
                float pb1 = __builtin_amdgcn_exp2f(s[ibt][kj + 2][1]);
                float pb2 = __builtin_amdgcn_exp2f(s[ibt][kj + 2][2]);
                float pb3 = __builtin_amdgcn_exp2f(s[ibt][kj + 2][3]);
                lp[ibt] += ((pa0 + pa1) + (pa2 + pa3)) + ((pb0 + pb1) + (pb2 + pb3));
                union { s16x8 v; u32 w[4]; } u;
                u.w[0] = pk2(pa0, pa1);
                u.w[1] = pk2(pa2, pa3);
                u.w[2] = pk2(pb0, pb1);
                u.w[3] = pk2(pb2, pb3);
                ap[ibt] = u.v;
            }
            #pragma unroll
            for (int dt = 0; dt < 4; ++dt)
                #pragma unroll
                for (int ibt = 0; ibt < 4; ++ibt)
                    o_acc[ibt][dt] = __builtin_amdgcn_mfma_f32_16x16x32_bf16(vc[kj][dt], ap[ibt], o_acc[ibt][dt], 0, 0, 0);
        }

        // rotate prefetched registers
        #pragma unroll
        for (int kd = 0; kd < 2; ++kd)
            #pragma unroll
            for (int jt = 0; jt < 4; ++jt)
                kc[kd][jt] = kn[kd][jt];
        #pragma unroll
        for (int kj = 0; kj < 2; ++kj)
            #pragma unroll
            for (int dt = 0; dt < 4; ++dt)
                vc[kj][dt] = vn[kj][dt];
    }

    #pragma unroll
    for (int ibt = 0; ibt < 4; ++ibt) {
        lp[ibt] += __shfl_xor(lp[ibt], 16);
        lp[ibt] += __shfl_xor(lp[ibt], 32);
    }

    // combine the two waves' j-partials: plain addition (sum-normalized softmax)
    if (wv == 1) {
        #pragma unroll
        for (int ibt = 0; ibt < 4; ++ibt) {
            #pragma unroll
            for (int dt = 0; dt < 4; ++dt)
                *(f32x4*)&o_sh[ibt * 16 + mn][dt * 16 + q * 4] = o_acc[ibt][dt];
            if (q == 0) lp_sh[ibt * 16 + mn] = lp[ibt];
        }
    }
    __syncthreads();
    if (wv == 0) {
        u16* Ab = aoP + (size_t)b * LDIM * 512;
        #pragma unroll
        for (int ibt = 0; ibt < 4; ++ibt) {
            const float rinv = 1.0f / (lp[ibt] + lp_sh[ibt * 16 + mn]);
            const int ltile = ib64 * 4 + ibt;
            #pragma unroll
            for (int dt = 0; dt < 4; ++dt) {
                f32x4 os = *(const f32x4*)&o_sh[ibt * 16 + mn][dt * 16 + q * 4];
                u16x4 pk;
                #pragma unroll
                for (int r = 0; r < 4; ++r)
                    pk[r] = f2b((o_acc[ibt][dt][r] + os[r]) * rinv);
                // packed-chunk store: col = h*64 + dt*16 + q*4 + r
                const int cstep = h * 2 + (dt >> 1);
                const int lanep = ((dt & 1) * 2 + (q >> 1)) * 16 + mn;
                u16* dst = Ab + ((size_t)(ltile * 16 + cstep) * 64 + lanep) * 8 + (q & 1) * 4;
                *(u16x4*)dst = pk;
            }
        }
    }
}

// ---------------- Output GEMM: packed-chunk loads + XCD swizzle ----------------
// 1-D grid 512: wg = xf*64 + (b*16+y) -> wg%8 = y%8: aoP B-tile sharers co-XCD.
__global__ __launch_bounds__(256)
void outgemm_d(const u16* __restrict__ aoP, const u16* __restrict__ WOP,
               const float* __restrict__ bias, float* __restrict__ Y)
{
    const int wg = blockIdx.x;
    const int xf = wg >> 6;              // 0..7
    const int yz = wg & 63;              // b*16 + y
    const int b  = yz >> 4;
    const int l0 = (yz & 15) * 128;
    const int f0 = xf * 64;
    const int t = threadIdx.x, w = t >> 6, lane = t & 63;
    const int mn = lane & 15, q = lane >> 4;
    const int mbase = f0 + (w >> 1) * 32;
    const int nbase = l0 + (w & 1) * 64;
    const u16* Abase = WOP + (size_t)mbase * CDIM;
    const u16* Bbase = aoP + ((size_t)b * LDIM + nbase) * CDIM;
    float* Yb = Y + (size_t)b * CDIM * LDIM;

    f32x4 acc[2][4] = {};
    #pragma unroll 2
    for (int c0 = 0; c0 < CDIM; c0 += 32) {
        s16x8 a[2], bf[4];
        #pragma unroll
        for (int mi = 0; mi < 2; ++mi)
            a[mi] = *(const s16x8*)(Abase + mi * 16 * CDIM + c0 * 16 + lane * 8);
        #pragma unroll
        for (int ni = 0; ni < 4; ++ni)
            bf[ni] = *(const s16x8*)(Bbase + ni * 16 * CDIM + c0 * 16 + lane * 8);
        #pragma unroll
        for (int mi = 0; mi < 2; ++mi)
            #pragma unroll
            for (int ni = 0; ni < 4; ++ni)
                acc[mi][ni] = __builtin_amdgcn_mfma_f32_16x16x32_bf16(a[mi], bf[ni], acc[mi][ni], 0, 0, 0);
    }
    #pragma unroll
    for (int mi = 0; mi < 2; ++mi)
        #pragma unroll
        for (int r = 0; r < 4; ++r) {
            const int f = mbase + mi * 16 + q * 4 + r;
            const float bs = bias[f];
            #pragma unroll
            for (int ni = 0; ni < 4; ++ni)
                Yb[(size_t)f * LDIM + nbase + ni * 16 + mn] = acc[mi][ni][r] + bs;
        }
}

extern "C" void kernel_launch(void* const* d_in, const int* in_sizes, int n_in,
                              void* d_out, int out_size, void* d_ws, size_t ws_size,
                              hipStream_t stream) {
    const float *x = nullptr, *w_qkv = nullptr, *w_out = nullptr, *b_out = nullptr;
    for (int i = 0; i < n_in; ++i) {
        switch (in_sizes[i]) {
            case 4 * 512 * 2048: x     = (const float*)d_in[i]; break;
            case 512 * 1536:     w_qkv = (const float*)d_in[i]; break;
            case 512 * 512:      w_out = (const float*)d_in[i]; break;
            case 512:            b_out = (const float*)d_in[i]; break;
        }
    }
    float* out = (float*)d_out;                 // [4][512][2048] f32

    const size_t SLAB = (size_t)BATCH * LDIM * 512;      // 4194304 elems
    u16* WOP = (u16*)d_ws;                               // [512 rows][512] packed
    u16* XP  = WOP + (size_t)512 * 512;                  // [4][2048 rows][512] packed
    u16* WP  = XP + SLAB;                                // [1536 rows][512] packed
    u16* QF  = WP + (size_t)1536 * 512;                  // [32][2048*64] attn-packed
    u16* KF  = QF + SLAB;                                // [32][2048*64] attn-packed
    u16* VF  = KF + SLAB;                                // [32][2048*64] attn-packed
    u16* aoP = VF + SLAB;                                // [4][2048 rows][512] packed

    transpA_k<<<dim3(8, 160), 256, 0, stream>>>(x, w_qkv, w_out, XP, WP, WOP);
    qkvgemm_bf16<<<dim3(1536), 256, 0, stream>>>(XP, WP, QF, KF, VF);
    attn_k<<<dim3(32, 32), 128, 0, stream>>>(QF, KF, VF, aoP);
    outgemm_d<<<dim3(512), 256, 0, stream>>>(aoP, WOP, b_out, out);
}